// Round 8
// baseline (496.449 us; speedup 1.0000x reference)
//
#include <hip/hip_runtime.h>

// LIF spiking-neuron forward -- THREE-PASS STREAM-SEPARATED version.
// inputs: (B,C,H,W,T) = (8,64,32,32,100) f32, T innermost (stride 1).
// outputs: syn, mem, spike -- each (B,C,H,W,T) f32, concatenated in d_out.
//
// Per pixel, sequential over t:
//   out_t    = (mem - 1 > 0) ? 1 : 0          (uses mem BEFORE update)
//   mem_next = (BETA*mem + syn) * (1 - out)   (uses OLD syn)
//   syn_next = ALPHA*syn + x_t
//
// NUMERICS: f64 recurrence, mul-then-add split by asm value barrier, exact
// double constants -- bit-identical FP ops to the r3-r7 passing kernels
// (absmax 2.375, threshold 2.74). Recomputing the identical instruction
// sequence per pass yields the identical trajectory.
//
// PERF rationale (r3-r7 synthesis): five different schedules all plateau at
// 2.2-2.8 TB/s with every pipe idle -> the HBM/L2 system is pattern-limited:
// chip-wide fine-grained interleave of 1 read + 3 write streams (4 regions x
// 1024 waves) defeats R/W scheduling. Compute is 5% busy -> recompute the
// recurrence 3x, one OUTPUT STREAM PER KERNEL:
//   K1 syn:   read input (full rows into regs), write syn   (1R + 1W clean)
//   K2 mem:   input likely L3-resident (210MB < 256MB), write mem
//   K3 spike: same, write spike
// Input loads: per-lane full-row bursts (13+12 float4) -> each 128B line
// requested once within a tight window (no inter-chunk straddle refetch).
// Output: r7-proven wave-private LDS slab transpose, no barriers anywhere.

typedef float f32x4 __attribute__((ext_vector_type(4)));

constexpr int    T_TOT = 100;
constexpr int    TC    = 20;          // timesteps per store round
constexpr int    NCH   = T_TOT / TC;  // 5 rounds
constexpr int    V4    = TC / 4;      // float4s per round = 5
constexpr int    NV4   = T_TOT / 4;   // float4s per full row = 25
constexpr int    ROWF  = 28;          // slab row stride (112B, 16B-aligned)
constexpr int    BLOCK = 256;
constexpr int    PPW   = 64;
constexpr int    PPB   = 256;
constexpr double ALPHA = 0.95;        // exact Python double
constexpr double BETA  = 0.9;         // exact Python double

// round-to-nearest mul then add in f64, contraction-proof. NOT volatile:
// if the result is dead (per-pass DCE of unused chains) it may be removed.
__device__ __forceinline__ double mul_add_rn64(double a, double b, double c) {
    double p = a * b;
    asm("" : "+v"(p));
    return p + c;
}

// SEL: 0 = syn, 1 = mem, 2 = spike
template <int SEL>
__global__ __launch_bounds__(BLOCK)
void lif_pass(const float* __restrict__ in, float* __restrict__ outp)
{
    const int tid  = threadIdx.x;
    const int lane = tid & 63;
    const int wv   = tid >> 6;
    const int pix0 = blockIdx.x * PPB + wv * PPW;
    const float* xp = in + (size_t)(pix0 + lane) * T_TOT;

    // full row in registers; burst A now, burst B after round 0
    f32x4 xb[NV4];
    #pragma unroll
    for (int e = 0; e < 13; ++e)
        xb[e] = *reinterpret_cast<const f32x4*>(xp + 4 * e);

    double syn = 0.0, mem = 0.0;   // f64 carry (bit-identical r3-r7 path)

    #pragma unroll                 // full unroll: xb indices must be static
    for (int c = 0; c < NCH; ++c) {
        if (c == 1) {              // burst B: issued one full round before use
            #pragma unroll
            for (int e = 13; e < NV4; ++e)
                xb[e] = *reinterpret_cast<const f32x4*>(xp + 4 * e);
        }

        float r[TC];               // the ONE tracked output this pass
        unsigned smask = 0u;
        {
            #pragma clang fp contract(off)
            #pragma unroll
            for (int j = 0; j < TC; ++j) {
                const int    t     = c * TC + j;
                const double x     = (double)xb[t >> 2][t & 3];
                const bool   o     = (mem - 1.0 > 0.0);
                const double om    = o ? 0.0 : 1.0;              // == (1 - out)
                const double mem_n = mul_add_rn64(BETA, mem, syn) * om;
                const double syn_n = mul_add_rn64(ALPHA, syn, x);
                if (SEL == 0) r[j] = (float)syn_n;
                if (SEL == 1) r[j] = (float)mem_n;
                if (SEL == 2) smask |= (o ? 1u : 0u) << j;
                syn = syn_n; mem = mem_n;   // unused chains DCE per SEL
            }
        }

        const int tb = c * TC;
        if constexpr (SEL < 2) {
            // wave-private slab transpose (r7-proven; in-order DS pipe, no barriers)
            __shared__ float tile[4 * PPW * ROWF];     // 28672 B
            float* slab = &tile[wv * PPW * ROWF];
            #pragma unroll
            for (int e = 0; e < V4; ++e) {
                f32x4 v;
                v.x = r[4*e]; v.y = r[4*e+1]; v.z = r[4*e+2]; v.w = r[4*e+3];
                *reinterpret_cast<f32x4*>(&slab[lane * ROWF + 4 * e]) = v;
            }
            #pragma unroll
            for (int k = 0; k < V4; ++k) {
                const int idx = lane + 64 * k;
                const int p   = idx / 5;
                const int e   = idx - 5 * p;
                const f32x4 v = *reinterpret_cast<const f32x4*>(&slab[p * ROWF + 4 * e]);
                *reinterpret_cast<f32x4*>(
                    outp + (size_t)(pix0 + p) * T_TOT + tb + 4 * e) = v;
            }
        } else {
            // spike: transpose the 20-bit mask via shuffle (no LDS at all)
            #pragma unroll
            for (int k = 0; k < V4; ++k) {
                const int idx = lane + 64 * k;
                const int p   = idx / 5;
                const int e   = idx - 5 * p;
                const unsigned m = (unsigned)__shfl((int)smask, p, 64);
                f32x4 v;
                v.x = ((m >> (4*e    )) & 1u) ? 1.0f : 0.0f;
                v.y = ((m >> (4*e + 1)) & 1u) ? 1.0f : 0.0f;
                v.z = ((m >> (4*e + 2)) & 1u) ? 1.0f : 0.0f;
                v.w = ((m >> (4*e + 3)) & 1u) ? 1.0f : 0.0f;
                *reinterpret_cast<f32x4*>(
                    outp + (size_t)(pix0 + p) * T_TOT + tb + 4 * e) = v;
            }
        }
    }
}

extern "C" void kernel_launch(void* const* d_in, const int* in_sizes, int n_in,
                              void* d_out, int out_size, void* d_ws, size_t ws_size,
                              hipStream_t stream) {
    const float* in = (const float*)d_in[0];
    float* out = (float*)d_out;

    const int n    = in_sizes[0];      // B*C*H*W*T = 52,428,800
    const int npix = n / T_TOT;        // 524,288

    float* syn_o = out;
    float* mem_o = out + (size_t)n;
    float* spk_o = out + 2 * (size_t)n;

    dim3 grid(npix / PPB);             // 2048 blocks per pass
    dim3 block(BLOCK);
    lif_pass<0><<<grid, block, 0, stream>>>(in, syn_o);
    lif_pass<1><<<grid, block, 0, stream>>>(in, mem_o);
    lif_pass<2><<<grid, block, 0, stream>>>(in, spk_o);
}

// Round 9
// 166.994 us; speedup vs baseline: 2.9729x; 2.9729x over previous
//
#include <hip/hip_runtime.h>

// LIF spiking-neuron forward -- DENSE-INSTRUCTION version.
// inputs: (B,C,H,W,T) = (8,64,32,32,100) f32, T innermost (stride 1).
// outputs: syn, mem, spike -- each (B,C,H,W,T) f32, concatenated in d_out.
//
// Per pixel, sequential over t:
//   out_t    = (mem - 1 > 0) ? 1 : 0          (uses mem BEFORE update)
//   mem_next = (BETA*mem + syn) * (1 - out)   (uses OLD syn)
//   syn_next = ALPHA*syn + x_t
//
// NUMERICS: f64 recurrence, mul-then-add split by asm value barrier, exact
// double constants -- bit-identical FP sequence to r3-r8 (absmax 2.375,
// threshold 2.74). Only data movement changed.
//
// PERF root-cause (r3-r8 synthesis): all prior variants plateaued at
// 2.2-2.8 TB/s because every global instruction touched 16B-or-80B pieces
// at 400B stride -> partial-line ECC RMW on stores (r6: WRITE 2x; r7: +22%)
// and low in-flight line count. The harness's fillBuffer proves 6.8 TB/s
// at 11% occupancy when each instruction writes full contiguous lines.
// r9: EVERY global load/store is lane-contiguous f32x4 -- 1KB (8 full
// lines) per instruction; 64-px task region = exactly 200 aligned lines.
// The pixel<->time transpose lives in a wave-private LDS slab:
//   dense load -> transposed deposit -> in-place recurrence (x overwritten
//   by syn) -> dense syn store -> refill (mem from regs) -> dense store ->
//   refill (spike from bitmask) -> dense store. Zero barriers (wave-
//   lockstep, in-order DS pipe -- r7-proven).

typedef float f32x4 __attribute__((ext_vector_type(4)));

constexpr int    T_TOT = 100;
constexpr int    NV4   = 25;     // float4 per pixel row
constexpr int    ROW4  = 26;     // slab row stride in float4 (pad: near-even banks)
constexpr int    PPW   = 64;     // pixels per wave-task
constexpr double ALPHA = 0.95;   // exact Python double
constexpr double BETA  = 0.9;    // exact Python double

// round-to-nearest mul then add in f64, contraction-proof.
__device__ __forceinline__ double mul_add_rn64(double a, double b, double c) {
    double p = a * b;
    asm("" : "+v"(p));
    return p + c;
}

// compile-time fence: forbid compiler reordering of LDS ops across phases
// (wave-lockstep + in-order DS pipe make it correct at HW level; zero instrs)
#define WAVE_FENCE()  do { __builtin_amdgcn_wave_barrier(); \
                           asm volatile("" ::: "memory"); } while (0)

// dense store of the slab to one output array: instruction k writes the
// contiguous 1KB [obase + k*1024, +1024) -- 8 full 128B lines, no RMW.
#define STORE_DENSE(OPTR)                                                     \
    do {                                                                      \
        float* ob = (OPTR) + (size_t)pix0 * T_TOT;                            \
        _Pragma("unroll")                                                     \
        for (int k = 0; k < NV4; ++k) {                                       \
            const int g  = 64 * k + lane;                                     \
            const int ps = g / 25;                                            \
            const int es = g - 25 * ps;                                       \
            const f32x4 v = slab[ps * ROW4 + es];                             \
            *reinterpret_cast<f32x4*>(ob + 4 * (size_t)g) = v;                \
        }                                                                     \
    } while (0)

__global__ __launch_bounds__(64)
void lif_fwd(const float* __restrict__ in,
             float* __restrict__ syn_o,
             float* __restrict__ mem_o,
             float* __restrict__ spk_o)
{
    __shared__ f32x4 slab[PPW * ROW4];     // 26624 B -> 6 blocks(waves)/CU

    const int lane = threadIdx.x;          // one wave per block
    const int pix0 = blockIdx.x * PPW;
    const float* ib = in + (size_t)pix0 * T_TOT;

    // ---- dense load + transposed deposit into slab ----
    // instr k reads contiguous 1KB; deposit scatters to [pixel][e] slots.
    #pragma unroll
    for (int k = 0; k < NV4; ++k) {
        const int g  = 64 * k + lane;                 // global float4 idx in task
        const f32x4 v = *reinterpret_cast<const f32x4*>(ib + 4 * (size_t)g);
        const int ps = g / 25;
        const int es = g - 25 * ps;
        slab[ps * ROW4 + es] = v;
    }
    WAVE_FENCE();

    // ---- recurrence (f64, bit-identical r3-r8 path); lane owns pixel ----
    // reads x b128 from its slab row, overwrites the slot with syn (f32).
    double syn = 0.0, mem = 0.0;
    f32x4 mv[NV4];                         // mem values, static-indexed -> VGPRs
    unsigned smask[4] = {0u, 0u, 0u, 0u};  // spike bits, static word index

    #pragma unroll
    for (int e = 0; e < NV4; ++e) {
        const f32x4 xv = slab[lane * ROW4 + e];
        f32x4 sv;
        {
            #pragma clang fp contract(off)
            #pragma unroll
            for (int j = 0; j < 4; ++j) {
                const int    t     = 4 * e + j;
                const double x     = (double)xv[j];
                const bool   o     = (mem - 1.0 > 0.0);
                const double om    = o ? 0.0 : 1.0;          // == (1 - out)
                const double mem_n = mul_add_rn64(BETA, mem, syn) * om;
                const double syn_n = mul_add_rn64(ALPHA, syn, x);
                sv[j]    = (float)syn_n;
                mv[e][j] = (float)mem_n;
                smask[t >> 5] |= (o ? 1u : 0u) << (t & 31);
                syn = syn_n; mem = mem_n;
            }
        }
        slab[lane * ROW4 + e] = sv;        // in-place: x just consumed
    }
    WAVE_FENCE();

    // ---- syn: dense store ----
    STORE_DENSE(syn_o);
    WAVE_FENCE();

    // ---- mem: refill slab from registers, dense store ----
    #pragma unroll
    for (int e = 0; e < NV4; ++e) slab[lane * ROW4 + e] = mv[e];
    WAVE_FENCE();
    STORE_DENSE(mem_o);
    WAVE_FENCE();

    // ---- spike: expand bitmask, refill, dense store ----
    #pragma unroll
    for (int e = 0; e < NV4; ++e) {
        f32x4 v;
        #pragma unroll
        for (int j = 0; j < 4; ++j) {
            const int t = 4 * e + j;
            v[j] = ((smask[t >> 5] >> (t & 31)) & 1u) ? 1.0f : 0.0f;
        }
        slab[lane * ROW4 + e] = v;
    }
    WAVE_FENCE();
    STORE_DENSE(spk_o);
}

extern "C" void kernel_launch(void* const* d_in, const int* in_sizes, int n_in,
                              void* d_out, int out_size, void* d_ws, size_t ws_size,
                              hipStream_t stream) {
    const float* in = (const float*)d_in[0];
    float* out = (float*)d_out;

    const int n    = in_sizes[0];      // B*C*H*W*T = 52,428,800
    const int npix = n / T_TOT;        // 524,288

    float* syn_o = out;
    float* mem_o = out + (size_t)n;
    float* spk_o = out + 2 * (size_t)n;

    dim3 grid(npix / PPW);             // 8192 one-wave tasks, no tail
    dim3 block(64);
    lif_fwd<<<grid, block, 0, stream>>>(in, syn_o, mem_o, spk_o);
}